// Round 1
// baseline (1814.729 us; speedup 1.0000x reference)
//
#include <hip/hip_runtime.h>
#include <hip/hip_bf16.h>
#include <math.h>

#define N_NODES 10000
#define FEAT    256
#define NEDGE   320000
#define NLAYERS 5
#define NOC     128

// ---------------- init: deg=1 (self loop), counters=0, attmax=0 ----------------
__global__ void k_init(float* deg, int* cnt, int* fill, int* attm) {
    int i = blockIdx.x * blockDim.x + threadIdx.x;
    if (i < N_NODES) { deg[i] = 1.0f; cnt[i] = 0; fill[i] = 0; }
    if (i < NLAYERS) attm[i] = 0;
}

// ---------------- degree + per-dst edge count ----------------
__global__ void k_count(const int* __restrict__ edges, const float* __restrict__ ew,
                        float* deg, int* cnt) {
    int e = blockIdx.x * blockDim.x + threadIdx.x;
    if (e >= NEDGE) return;
    int d = edges[NEDGE + e];
    atomicAdd(&deg[d], ew[e]);
    atomicAdd(&cnt[d], 1);
}

// ---------------- dinv = rsqrt(deg) in place ----------------
__global__ void k_dinv(float* deg) {
    int i = blockIdx.x * blockDim.x + threadIdx.x;
    if (i < N_NODES) {
        float dg = deg[i];
        deg[i] = (dg > 0.f) ? 1.0f / sqrtf(dg) : 0.f;
    }
}

// ---------------- single-block exclusive scan (10000 entries) ----------------
__global__ void k_scan(const int* __restrict__ cnt, int* __restrict__ ptr) {
    __shared__ int sm[1024];
    __shared__ int carry;
    int t = threadIdx.x;
    if (t == 0) carry = 0;
    __syncthreads();
    for (int base = 0; base < N_NODES; base += 1024) {
        int i = base + t;
        int v = (i < N_NODES) ? cnt[i] : 0;
        sm[t] = v;
        __syncthreads();
        for (int off = 1; off < 1024; off <<= 1) {
            int add = (t >= off) ? sm[t - off] : 0;
            __syncthreads();
            sm[t] += add;
            __syncthreads();
        }
        if (i < N_NODES) ptr[i] = carry + sm[t] - v;   // exclusive
        __syncthreads();
        if (t == 1023) carry += sm[1023];
        __syncthreads();
    }
    if (t == 0) ptr[N_NODES] = carry;
}

// ---------------- CSR fill: col + normalized coefficient ----------------
__global__ void k_fill(const int* __restrict__ edges, const float* __restrict__ ew,
                       const float* __restrict__ dinv, const int* __restrict__ ptr,
                       int* fill, int* __restrict__ col, float* __restrict__ val) {
    int e = blockIdx.x * blockDim.x + threadIdx.x;
    if (e >= NEDGE) return;
    int s = edges[e], d = edges[NEDGE + e];
    int pos = ptr[d] + atomicAdd(&fill[d], 1);
    col[pos] = s;
    val[pos] = dinv[s] * ew[e] * dinv[d];
}

// ---------------- SpMM gather: t[row] = dinv[row]^2*x[row] + sum c_e * x[col_e]
// one wave (64 lanes) per row, float4 per lane covers 256 feats
__global__ __launch_bounds__(256) void k_spmm(const float* __restrict__ x,
        const int* __restrict__ ptr, const int* __restrict__ col,
        const float* __restrict__ val, const float* __restrict__ dinv,
        float* __restrict__ t) {
    int wave = threadIdx.x >> 6;
    int lane = threadIdx.x & 63;
    int row = blockIdx.x * 4 + wave;
    if (row >= N_NODES) return;
    float di = dinv[row];
    float selfc = di * di;
    float4 xv = ((const float4*)(x + (size_t)row * FEAT))[lane];
    float4 acc;
    acc.x = selfc * xv.x; acc.y = selfc * xv.y; acc.z = selfc * xv.z; acc.w = selfc * xv.w;
    int e0 = ptr[row], e1 = ptr[row + 1];
    for (int e = e0; e < e1; ++e) {
        int c = col[e];
        float cv = val[e];
        float4 v = ((const float4*)(x + (size_t)c * FEAT))[lane];
        acc.x += cv * v.x; acc.y += cv * v.y; acc.z += cv * v.z; acc.w += cv * v.w;
    }
    ((float4*)(t + (size_t)row * FEAT))[lane] = acc;
}

// ---------------- tiled fp32 GEMM: C[M,N] = A[M,K]@B[K,N] + bias (+relu+max)
// 64x64 tile, 256 threads, 4x4 per thread. chunked: A[n,k] = feats[(k>>8)*10000+n][k&255]
__global__ __launch_bounds__(256) void k_gemm(const float* __restrict__ A,
        const float* __restrict__ B, const float* __restrict__ bias,
        float* __restrict__ C, int M, int N, int K, int chunked,
        int* attm, int do_relu) {
    __shared__ float As[16][68];
    __shared__ float Bs[16][68];
    int tid = threadIdx.x;
    int tx = tid & 15, ty = tid >> 4;
    int m0 = blockIdx.x * 64, n0 = blockIdx.y * 64;
    float acc[4][4];
#pragma unroll
    for (int i = 0; i < 4; ++i)
#pragma unroll
        for (int j = 0; j < 4; ++j) acc[i][j] = 0.f;

    int arow = m0 + (tid >> 2); if (arow >= M) arow = M - 1;
    int am = tid >> 2;
    int akk = (tid & 3) * 4;
    int bk = tid >> 4;
    int bn = (tid & 15) * 4;

    for (int k0 = 0; k0 < K; k0 += 16) {
        int ka = k0 + akk;
        float4 av;
        if (chunked)
            av = *(const float4*)(A + ((size_t)(ka >> 8) * N_NODES + arow) * FEAT + (ka & 255));
        else
            av = *(const float4*)(A + (size_t)arow * K + ka);
        float4 bv = *(const float4*)(B + (size_t)(k0 + bk) * N + (n0 + bn));
        __syncthreads();
        As[akk + 0][am] = av.x;
        As[akk + 1][am] = av.y;
        As[akk + 2][am] = av.z;
        As[akk + 3][am] = av.w;
        *(float4*)&Bs[bk][bn] = bv;
        __syncthreads();
#pragma unroll
        for (int kk = 0; kk < 16; ++kk) {
            float4 a4 = *(const float4*)&As[kk][ty * 4];
            float4 b4 = *(const float4*)&Bs[kk][tx * 4];
            float a[4] = {a4.x, a4.y, a4.z, a4.w};
            float b[4] = {b4.x, b4.y, b4.z, b4.w};
#pragma unroll
            for (int i = 0; i < 4; ++i)
#pragma unroll
                for (int j = 0; j < 4; ++j) acc[i][j] += a[i] * b[j];
        }
    }

    float lmax = 0.f;
#pragma unroll
    for (int i = 0; i < 4; ++i) {
        int m = m0 + ty * 4 + i;
        if (m < M) {
            float vals[4];
#pragma unroll
            for (int j = 0; j < 4; ++j) {
                float v = acc[i][j] + bias[n0 + tx * 4 + j];
                if (do_relu) { v = fmaxf(v, 0.f); lmax = fmaxf(lmax, v); }
                vals[j] = v;
            }
            *(float4*)(C + (size_t)m * N + n0 + tx * 4) =
                make_float4(vals[0], vals[1], vals[2], vals[3]);
        }
    }
    if (do_relu) {
        __syncthreads();
        float* red = (float*)As;
        red[tid] = lmax;
        __syncthreads();
        for (int s = 128; s > 0; s >>= 1) {
            if (tid < s) red[tid] = fmaxf(red[tid], red[tid + s]);
            __syncthreads();
        }
        if (tid == 0) atomicMax(attm, __float_as_int(red[0]));  // all values >= 0
    }
}

// ---------------- attention MLP (5 -> 25 relu -> 5 sigmoid), one tiny block ----
__global__ void k_att(const int* __restrict__ attm, const float* __restrict__ fc1w,
                      const float* __restrict__ fc1b, const float* __restrict__ fc2w,
                      const float* __restrict__ fc2b, float* __restrict__ att) {
    __shared__ float a0[NLAYERS], a1[5 * NLAYERS];
    int t = threadIdx.x;
    if (t < NLAYERS) a0[t] = __int_as_float(attm[t]);
    __syncthreads();
    if (t < 5 * NLAYERS) {
        float s = fc1b[t];
        for (int c = 0; c < NLAYERS; ++c) s += fc1w[t * NLAYERS + c] * a0[c];
        a1[t] = fmaxf(s, 0.f);
    }
    __syncthreads();
    if (t < NLAYERS) {
        float s = fc2b[t];
        for (int c = 0; c < 5 * NLAYERS; ++c) s += fc2w[t * 5 * NLAYERS + c] * a1[c];
        att[t] = 1.f / (1.f + expf(-s));
    }
}

// ---------------- B'[k*128+o] = cw[o*1280+k] * att[k>>8] ----------------
__global__ void k_bprime(const float* __restrict__ cw, const float* __restrict__ att,
                         float* __restrict__ bp) {
    int idx = blockIdx.x * blockDim.x + threadIdx.x;
    if (idx >= NLAYERS * FEAT * NOC) return;
    int k = idx >> 7;                       // 0..1279
    int o = idx & (NOC - 1);
    bp[idx] = cw[(size_t)o * (NLAYERS * FEAT) + k] * att[k >> 8];
}

// ---------------- final C[10000,10000] = X[10000,128] @ Y[10000,128]^T --------
// 128x128 tile, 256 threads, 8x8 per thread
__global__ __launch_bounds__(256) void k_final(const float* __restrict__ X,
        const float* __restrict__ Y, float* __restrict__ C) {
    __shared__ float Xs[16][132];
    __shared__ float Ys[16][132];
    int tid = threadIdx.x;
    int tx = tid & 15, ty = tid >> 4;
    int m0 = blockIdx.x * 128, n0 = blockIdx.y * 128;
    float acc[8][8];
#pragma unroll
    for (int i = 0; i < 8; ++i)
#pragma unroll
        for (int j = 0; j < 8; ++j) acc[i][j] = 0.f;

    int lrow = tid >> 1;
    int lk = (tid & 1) * 8;
    int xrow = m0 + lrow; if (xrow >= N_NODES) xrow = N_NODES - 1;
    int yrow = n0 + lrow; if (yrow >= N_NODES) yrow = N_NODES - 1;

    for (int k0 = 0; k0 < NOC; k0 += 16) {
        float4 xv0 = *(const float4*)(X + (size_t)xrow * NOC + k0 + lk);
        float4 xv1 = *(const float4*)(X + (size_t)xrow * NOC + k0 + lk + 4);
        float4 yv0 = *(const float4*)(Y + (size_t)yrow * NOC + k0 + lk);
        float4 yv1 = *(const float4*)(Y + (size_t)yrow * NOC + k0 + lk + 4);
        __syncthreads();
        Xs[lk + 0][lrow] = xv0.x; Xs[lk + 1][lrow] = xv0.y;
        Xs[lk + 2][lrow] = xv0.z; Xs[lk + 3][lrow] = xv0.w;
        Xs[lk + 4][lrow] = xv1.x; Xs[lk + 5][lrow] = xv1.y;
        Xs[lk + 6][lrow] = xv1.z; Xs[lk + 7][lrow] = xv1.w;
        Ys[lk + 0][lrow] = yv0.x; Ys[lk + 1][lrow] = yv0.y;
        Ys[lk + 2][lrow] = yv0.z; Ys[lk + 3][lrow] = yv0.w;
        Ys[lk + 4][lrow] = yv1.x; Ys[lk + 5][lrow] = yv1.y;
        Ys[lk + 6][lrow] = yv1.z; Ys[lk + 7][lrow] = yv1.w;
        __syncthreads();
#pragma unroll
        for (int kk = 0; kk < 16; ++kk) {
            float a[8], b[8];
            *(float4*)&a[0] = *(const float4*)&Xs[kk][ty * 8];
            *(float4*)&a[4] = *(const float4*)&Xs[kk][ty * 8 + 4];
            *(float4*)&b[0] = *(const float4*)&Ys[kk][tx * 8];
            *(float4*)&b[4] = *(const float4*)&Ys[kk][tx * 8 + 4];
#pragma unroll
            for (int i = 0; i < 8; ++i)
#pragma unroll
                for (int j = 0; j < 8; ++j) acc[i][j] += a[i] * b[j];
        }
    }

    bool full = (m0 + 127 < N_NODES) && (n0 + 127 < N_NODES);
    if (full) {
#pragma unroll
        for (int i = 0; i < 8; ++i) {
            size_t row = (size_t)(m0 + ty * 8 + i) * N_NODES + n0 + tx * 8;
            *(float4*)(C + row)     = make_float4(acc[i][0], acc[i][1], acc[i][2], acc[i][3]);
            *(float4*)(C + row + 4) = make_float4(acc[i][4], acc[i][5], acc[i][6], acc[i][7]);
        }
    } else {
        for (int i = 0; i < 8; ++i) {
            int m = m0 + ty * 8 + i;
            if (m >= N_NODES) continue;
            for (int j = 0; j < 8; ++j) {
                int c = n0 + tx * 8 + j;
                if (c < N_NODES) C[(size_t)m * N_NODES + c] = acc[i][j];
            }
        }
    }
}

extern "C" void kernel_launch(void* const* d_in, const int* in_sizes, int n_in,
                              void* d_out, int out_size, void* d_ws, size_t ws_size,
                              hipStream_t stream) {
    (void)in_sizes; (void)n_in; (void)out_size; (void)ws_size;

    // ---- workspace carve-up (~75.1 MB) ----
    float* ws     = (float*)d_ws;
    float* feats  = ws;                          // 5*10000*256 = 12,800,000
    float* tbuf   = feats + 12800000;            // 2,560,000
    float* outx   = tbuf + 2560000;              // 1,280,000
    float* outy   = outx + 1280000;              // 1,280,000
    float* dinv   = outy + 1280000;              // 10,016 (deg -> dinv in place)
    float* val    = dinv + 10016;                // 320,000
    float* bprime = val + 320000;                // 163,840
    float* attF   = bprime + 163840;             // 16
    int*   ptr    = (int*)(attF + 16);           // 10,016
    int*   cnt    = ptr + 10016;                 // 10,016
    int*   fill   = cnt + 10016;                 // 10,016
    int*   col    = fill + 10016;                // 320,000
    int*   attm   = col + 320000;                // 16

    for (int b = 0; b < 2; ++b) {
        const float* x0   = (const float*)d_in[b == 0 ? 0 : 1];
        const float* ew   = (const float*)d_in[b == 0 ? 2 : 3];
        const float* W    = (const float*)d_in[b == 0 ? 4 : 6];
        const float* bias = (const float*)d_in[b == 0 ? 5 : 7];
        const float* fc1w = (const float*)d_in[b == 0 ? 8 : 12];
        const float* fc1b = (const float*)d_in[b == 0 ? 9 : 13];
        const float* fc2w = (const float*)d_in[b == 0 ? 10 : 14];
        const float* fc2b = (const float*)d_in[b == 0 ? 11 : 15];
        const float* cw   = (const float*)d_in[b == 0 ? 16 : 18];
        const float* cb   = (const float*)d_in[b == 0 ? 17 : 19];
        const int* edges  = (const int*)d_in[b == 0 ? 20 : 21];
        float* outb = (b == 0) ? outx : outy;

        k_init<<<40, 256, 0, stream>>>(dinv, cnt, fill, attm);
        k_count<<<1250, 256, 0, stream>>>(edges, ew, dinv, cnt);
        k_dinv<<<40, 256, 0, stream>>>(dinv);
        k_scan<<<1, 1024, 0, stream>>>(cnt, ptr);
        k_fill<<<1250, 256, 0, stream>>>(edges, ew, dinv, ptr, fill, col, val);

        for (int l = 0; l < NLAYERS; ++l) {
            const float* prev = (l == 0) ? x0 : (feats + (size_t)(l - 1) * N_NODES * FEAT);
            k_spmm<<<2500, 256, 0, stream>>>(prev, ptr, col, val, dinv, tbuf);
            k_gemm<<<dim3(157, 4), 256, 0, stream>>>(
                tbuf, W + (size_t)l * FEAT * FEAT, bias + (size_t)l * FEAT,
                feats + (size_t)l * N_NODES * FEAT,
                N_NODES, FEAT, FEAT, 0, attm + l, 1);
        }

        k_att<<<1, 64, 0, stream>>>(attm, fc1w, fc1b, fc2w, fc2b, attF);
        k_bprime<<<640, 256, 0, stream>>>(cw, attF, bprime);
        k_gemm<<<dim3(157, 2), 256, 0, stream>>>(
            feats, bprime, cb, outb, N_NODES, NOC, NLAYERS * FEAT, 1, nullptr, 0);
    }

    k_final<<<dim3(79, 79), 256, 0, stream>>>(outx, outy, (float*)d_out);
}